// Round 7
// baseline (404.329 us; speedup 1.0000x reference)
//
#include <hip/hip_runtime.h>

#define D_MODEL 2048
#define S_LEN 2048
#define HQ 16
#define HKV 4
#define DH 128
#define QKV_W 3072
#define M_TOK 8192

typedef unsigned short u16;
typedef __bf16 bf16x8 __attribute__((ext_vector_type(8)));
typedef float f32x4 __attribute__((ext_vector_type(4)));
typedef float f32x16 __attribute__((ext_vector_type(16)));

__device__ __forceinline__ u16 f2bf(float f) {
  union { float f; unsigned u; } v; v.f = f;
  unsigned u = v.u;
  return (u16)((u + 0x7fffu + ((u >> 16) & 1u)) >> 16);
}

__device__ __forceinline__ bf16x8 ld_frag(const u16* p) {
  bf16x8 r; __builtin_memcpy(&r, p, 16); return r;
}

__device__ __forceinline__ void gl_lds16(const u16* g, u16* l) {
  __builtin_amdgcn_global_load_lds(
      (const __attribute__((address_space(1))) void*)g,
      (__attribute__((address_space(3))) void*)l, 16, 0, 0);
}

__device__ __forceinline__ unsigned cvtpk(float lo, float hi_) {
  unsigned r;
  asm("v_cvt_pk_bf16_f32 %0, %1, %2" : "=v"(r) : "v"(lo), "v"(hi_));
  return r;
}

__device__ __forceinline__ float exp2a(float x) {
  float r; asm("v_exp_f32 %0, %1" : "=v"(r) : "v"(x)); return r;
}

__device__ __forceinline__ float fmax3(float a, float b, float c) {
  float r;
  asm("v_max3_f32 %0, %1, %2, %3" : "=v"(r) : "v"(a), "v"(b), "v"(c));
  return r;
}

#define MFMA(a, b, c) __builtin_amdgcn_mfma_f32_16x16x32_bf16(a, b, c, 0, 0, 0)
#define MFMA32(a, b, c) __builtin_amdgcn_mfma_f32_32x32x16_bf16(a, b, c, 0, 0, 0)

__device__ __forceinline__ float vmax16(const f32x16& v) {
  float a = fmax3(v[0], v[1], v[2]);
  float b = fmax3(v[3], v[4], v[5]);
  float c = fmax3(v[6], v[7], v[8]);
  float d = fmax3(v[9], v[10], v[11]);
  float e = fmax3(v[12], v[13], v[14]);
  float f_ = fmax3(a, b, v[15]);
  float g = fmax3(c, d, e);
  return fmaxf(f_, g);
}

// ---------------- fp32 -> bf16 convert (optionally scale first scale_n) ----
__global__ __launch_bounds__(256) void k_f32_to_bf16(const float* __restrict__ s,
                                                     u16* __restrict__ d,
                                                     long scale_n) {
  long i = (long)(blockIdx.x * 256 + threadIdx.x) * 8;
  // Q pre-scale: log2(e)/sqrt(128)  (softmax runs in exp2 domain)
  float sc = (i < scale_n) ? 0.12751879677296637f : 1.0f;
  float a[8];
  __builtin_memcpy(a, s + i, 32);
  u16 r[8];
#pragma unroll
  for (int j = 0; j < 8; ++j) r[j] = f2bf(a[j] * sc);
  __builtin_memcpy(d + i, r, 16);
}

// ---------------- 256x256 quad-buffered GEMM  C = A[M,K] * B[N,K]^T --------
template <int OUT_BF16>
__global__ __launch_bounds__(512, 2) void k_gemm256(const u16* __restrict__ A,
                                                    const u16* __restrict__ B,
                                                    void* __restrict__ C,
                                                    int M, int N, int K) {
  __shared__ __attribute__((aligned(16))) u16 As[4][8192];  // 4 x 16KB
  __shared__ __attribute__((aligned(16))) u16 Bs[4][8192];
  const int tid = threadIdx.x;
  const int lane = tid & 63;
  const int wid = tid >> 6;
  const int l15 = lane & 15, l4 = lane >> 4;
  const int wr = wid >> 2, wc = wid & 3;  // 2x4 waves -> 128x64 out each

  const int xcd = blockIdx.x & 7;
  const int slot = blockIdx.x >> 3;
  const long tm = (long)(xcd * 4 + (slot & 3)) * 256;
  const long tn = (long)(slot >> 2) * 256;

  const int cA = l4 ^ ((l15 >> 1) & 3);
  const int arow = wr * 128 + l15;
  const int brow = wc * 64 + l15;

  f32x4 acc[8][4] = {};
  bf16x8 af[4], bfr[4];

#define STG(dst, src, tbase, t_)                                          \
  do {                                                                    \
    _Pragma("unroll") for (int j = 0; j < 2; ++j) {                       \
      int p = tid + j * 512;                                              \
      int row = p >> 2, cc = p & 3;                                       \
      int g = cc ^ ((row >> 1) & 3);                                      \
      gl_lds16(src + (tbase + row) * (long)K + (long)(t_) * 32 + g * 8,   \
               (dst) + p * 8);                                            \
    }                                                                     \
  } while (0)

#define DSR_A(ptr, mh)                                                    \
  _Pragma("unroll") for (int m = 0; m < 4; ++m)                           \
      af[m] = ld_frag((ptr) + (arow + (mh) * 64 + m * 16) * 32 + cA * 8);
#define DSR_B(ptr)                                                        \
  _Pragma("unroll") for (int n = 0; n < 4; ++n)                           \
      bfr[n] = ld_frag((ptr) + (brow + n * 16) * 32 + cA * 8);
#define MM(mh)                                                            \
  _Pragma("unroll") for (int m = 0; m < 4; ++m)                           \
      _Pragma("unroll") for (int n = 0; n < 4; ++n)                       \
          acc[(mh) * 4 + m][n] = MFMA(af[m], bfr[n], acc[(mh) * 4 + m][n]);
#define LGKM0                                              \
  asm volatile("s_waitcnt lgkmcnt(0)" ::: "memory");       \
  __builtin_amdgcn_sched_barrier(0)

  const int NT = K >> 5;  // BK=32
  STG(&As[0][0], A, tm, 0); STG(&Bs[0][0], B, tn, 0);
  STG(&As[1][0], A, tm, 1); STG(&Bs[1][0], B, tn, 1);
  STG(&As[2][0], A, tm, 2); STG(&Bs[2][0], B, tn, 2);
  asm volatile("s_waitcnt vmcnt(8)" ::: "memory");
  __builtin_amdgcn_s_barrier();

  for (int t = 0; t < NT; ++t) {
    const u16* as_ = &As[t & 3][0];
    const u16* bs_ = &Bs[t & 3][0];
    u16* an_ = &As[(t + 3) & 3][0];
    u16* bn_ = &Bs[(t + 3) & 3][0];
    const bool st = (t + 3 < NT);

    DSR_A(as_, 0);
    DSR_B(bs_);
    if (st) STG(an_, A, tm, t + 3);
    __builtin_amdgcn_s_barrier();
    LGKM0;
    __builtin_amdgcn_s_setprio(1); MM(0); __builtin_amdgcn_s_setprio(0);
    __builtin_amdgcn_s_barrier();

    DSR_A(as_, 1);
    if (st) STG(bn_, B, tn, t + 3);
    __builtin_amdgcn_s_barrier();
    LGKM0;
    __builtin_amdgcn_s_setprio(1); MM(1); __builtin_amdgcn_s_setprio(0);
    if (t + 3 < NT) {
      asm volatile("s_waitcnt vmcnt(8)" ::: "memory");
    } else if (t + 2 < NT) {
      asm volatile("s_waitcnt vmcnt(4)" ::: "memory");
    } else if (t + 1 < NT) {
      asm volatile("s_waitcnt vmcnt(0)" ::: "memory");
    }
    __builtin_amdgcn_s_barrier();
  }
#undef STG
#undef DSR_A
#undef DSR_B
#undef MM
#undef LGKM0

#pragma unroll
  for (int m = 0; m < 8; ++m)
#pragma unroll
    for (int n = 0; n < 4; ++n)
#pragma unroll
      for (int i = 0; i < 4; ++i) {
        long row = tm + wr * 128 + m * 16 + l4 * 4 + i;
        long col = tn + wc * 64 + n * 16 + l15;
        if (OUT_BF16)
          ((u16*)C)[row * N + col] = f2bf(acc[m][n][i]);
        else
          ((float*)C)[row * N + col] = acc[m][n][i];
      }
}

// ---------------- V transpose: qkv V-part [s,d] -> vt[b,kv][d][s] ----------
__global__ __launch_bounds__(256) void k_vtrans(const u16* __restrict__ qkv,
                                                u16* __restrict__ vt) {
  __shared__ u16 T[64][68];
  const int tid = threadIdx.x;
  const int st = blockIdx.x;
  const int dt = blockIdx.y;
  const int bh = blockIdx.z;
  const int b = bh >> 2, kvh = bh & 3;
  const long s0 = (long)st * 64, d0 = (long)dt * 64;
#pragma unroll
  for (int j = 0; j < 2; ++j) {
    int chunk = tid + j * 256;
    int row = chunk >> 3, c8 = chunk & 7;
    u16 tmp[8];
    __builtin_memcpy(tmp,
                     qkv + ((long)b * S_LEN + s0 + row) * QKV_W + 2560 +
                         kvh * DH + d0 + c8 * 8,
                     16);
    __builtin_memcpy(&T[row][c8 * 8], tmp, 16);
  }
  __syncthreads();
#pragma unroll
  for (int j = 0; j < 2; ++j) {
    int chunk = tid + j * 256;
    int drow = chunk >> 3, c8 = chunk & 7;
    u16 tmp[8];
#pragma unroll
    for (int e = 0; e < 8; ++e) tmp[e] = T[c8 * 8 + e][drow];
    __builtin_memcpy(vt + ((long)bh * DH + d0 + drow) * S_LEN + s0 + c8 * 8,
                     tmp, 16);
  }
}

// ---------------- flash attention, 8-wave 32x32 swapped-QK^T ---------------
// T4 counted-vmcnt pipeline (never vmcnt(0) in main loop), kt unrolled x2
// for static LDS bases, exp2-domain softmax, denominator via ones-MFMA.
__global__ __launch_bounds__(512, 2) void k_attn(const u16* __restrict__ qkv,
                                                 const u16* __restrict__ vt,
                                                 u16* __restrict__ ao) {
  __shared__ __attribute__((aligned(16))) u16 Ks[2][8192];
  __shared__ __attribute__((aligned(16))) u16 Vs[2][8192];
  const int tid = threadIdx.x;
  const int lane = tid & 63;
  const int wid = tid >> 6;
  const int l31 = lane & 31, hi = lane >> 5;
  const int qt = blockIdx.x & 7;
  const int hh = (blockIdx.x >> 3) & 3;
  const int bkv = blockIdx.x >> 5;
  const int b = bkv >> 2, kvh = bkv & 3;
  const int h = kvh * 4 + hh;
  const long rowbase = (long)b * S_LEN;
  const int q0 = qt * 256 + wid * 32;
  const long vbase = (long)bkv * DH * S_LEN;

  bf16x8 qf[8];
  {
    const u16* qrow = qkv + (rowbase + q0 + l31) * QKV_W + h * DH;
#pragma unroll
    for (int kk = 0; kk < 8; ++kk) qf[kk] = ld_frag(qrow + kk * 16 + hi * 8);
  }

  bf16x8 onesf;
  {
    union { u16 u[8]; bf16x8 v; } t;
#pragma unroll
    for (int e = 0; e < 8; ++e) t.u[e] = 0x3F80;  // bf16 1.0
    onesf = t.v;
  }

  f32x16 o[4] = {};   // C[d][q], q = l31
  f32x16 osum = {};   // running denominator per q (all regs equal)
  float m_run = -3.0e38f;

#define STAGE(KDST, VDST, tile)                                               \
  do {                                                                        \
    long s0_ = (long)(tile) * 64;                                             \
    _Pragma("unroll") for (int j = 0; j < 2; ++j) {                           \
      int chunk = (wid * 2 + j) * 64 + lane;                                  \
      int row = chunk >> 4, cc = chunk & 15;                                  \
      gl_lds16(qkv + (rowbase + s0_ + row) * QKV_W + 2048 + kvh * DH +        \
                   ((cc ^ (row & 7)) * 8),                                    \
               &(KDST)[chunk * 8]);                                           \
    }                                                                         \
    _Pragma("unroll") for (int j = 0; j < 2; ++j) {                           \
      int chunk = (wid * 2 + j) * 64 + lane;                                  \
      int row = chunk >> 3, cc = chunk & 7;                                   \
      gl_lds16(vt + vbase + (long)row * S_LEN + s0_ + ((cc ^ (row & 7)) * 8), \
               &(VDST)[chunk * 8]);                                           \
    }                                                                         \
  } while (0)

#define PROCESS(KSP, VSP)                                                     \
  {                                                                           \
    f32x16 p0 = {}, p1 = {};                                                  \
    __builtin_amdgcn_s_setprio(1);                                            \
    _Pragma("unroll") for (int kk = 0; kk < 8; ++kk) {                        \
      int ch0 = ((2 * kk + hi) ^ (l31 & 7));                                  \
      int ch1 = ((2 * kk + hi) ^ ((l31 + 32) & 7));                           \
      bf16x8 kf0 = ld_frag((KSP) + l31 * 128 + ch0 * 8);                      \
      bf16x8 kf1 = ld_frag((KSP) + (32 + l31) * 128 + ch1 * 8);               \
      p0 = MFMA32(kf0, qf[kk], p0);                                           \
      p1 = MFMA32(kf1, qf[kk], p1);                                           \
    }                                                                         \
    __builtin_amdgcn_s_setprio(0);                                            \
    float mx = fmaxf(vmax16(p0), vmax16(p1));                                 \
    mx = fmaxf(mx, __shfl_xor(mx, 32, 64));                                   \
    if (__any(mx > m_run + 11.0f)) {                                          \
      float nm = fmaxf(m_run, mx);                                            \
      float alpha = exp2a(m_run - nm);                                        \
      m_run = nm;                                                             \
      _Pragma("unroll") for (int r = 0; r < 16; ++r) osum[r] *= alpha;        \
      _Pragma("unroll") for (int n2 = 0; n2 < 4; ++n2)                        \
          _Pragma("unroll") for (int r = 0; r < 16; ++r) o[n2][r] *= alpha;   \
    }                                                                         \
    _Pragma("unroll") for (int r = 0; r < 16; ++r) {                          \
      p0[r] = exp2a(p0[r] - m_run);                                           \
      p1[r] = exp2a(p1[r] - m_run);                                           \
    }                                                                         \
    __builtin_amdgcn_s_setprio(1);                                            \
    _Pragma("unroll") for (int ks_ = 0; ks_ < 4; ++ks_) {                     \
      const f32x16& pp = (ks_ < 2) ? p0 : p1;                                 \
      const int bb = 8 * (ks_ & 1);                                           \
      unsigned A0 = cvtpk(pp[bb + 0], pp[bb + 1]);                            \
      unsigned A1 = cvtpk(pp[bb + 2], pp[bb + 3]);                            \
      unsigned B0 = cvtpk(pp[bb + 4], pp[bb + 5]);                            \
      unsigned B1 = cvtpk(pp[bb + 6], pp[bb + 7]);                            \
      asm volatile("v_permlane32_swap_b32 %0, %1" : "+v"(A0), "+v"(B0));      \
      asm volatile("v_permlane32_swap_b32 %0, %1" : "+v"(A1), "+v"(B1));      \
      union { unsigned u[4]; bf16x8 v; } pu;                                  \
      pu.u[0] = A0; pu.u[1] = A1; pu.u[2] = B0; pu.u[3] = B1;                 \
      osum = MFMA32(onesf, pu.v, osum);                                       \
      _Pragma("unroll") for (int n2 = 0; n2 < 4; ++n2) {                      \
        int vr = n2 * 32 + l31;                                               \
        int ch = ((2 * ks_ + hi) ^ (vr & 7));                                 \
        bf16x8 vf = ld_frag((VSP) + vr * 64 + ch * 8);                        \
        o[n2] = MFMA32(vf, pu.v, o[n2]);                                      \
      }                                                                       \
    }                                                                         \
    __builtin_amdgcn_s_setprio(0);                                            \
  }

  STAGE(Ks[0], Vs[0], 0);

  for (int kt2 = 0; kt2 < 16; ++kt2) {
    const bool tail = (kt2 == 15);
    // even tile -> buf0 ; prefetch odd tile into buf1
    STAGE(Ks[1], Vs[1], 2 * kt2 + 1);
    asm volatile("s_waitcnt vmcnt(4)" ::: "memory");
    __builtin_amdgcn_s_barrier();
    PROCESS(&Ks[0][0], &Vs[0][0]);
    __builtin_amdgcn_s_barrier();
    // odd tile -> buf1 ; prefetch next even tile into buf0
    if (!tail) {
      STAGE(Ks[0], Vs[0], 2 * kt2 + 2);
      asm volatile("s_waitcnt vmcnt(4)" ::: "memory");
    } else {
      asm volatile("s_waitcnt vmcnt(0)" ::: "memory");
    }
    __builtin_amdgcn_s_barrier();
    PROCESS(&Ks[1][0], &Vs[1][0]);
    __builtin_amdgcn_s_barrier();
  }

  {
    float inv = 1.0f / osum[0];
    u16* orow = ao + (rowbase + q0 + l31) * D_MODEL + h * DH;
#pragma unroll
    for (int n2 = 0; n2 < 4; ++n2)
#pragma unroll
      for (int g = 0; g < 4; ++g) {
        u16 tmp[4];
#pragma unroll
        for (int e = 0; e < 4; ++e) tmp[e] = f2bf(o[n2][g * 4 + e] * inv);
        __builtin_memcpy(orow + n2 * 32 + g * 8 + 4 * hi, tmp, 8);
      }
  }
#undef STAGE
#undef PROCESS
}

// ---------------------------------------------------------------------------
extern "C" void kernel_launch(void* const* d_in, const int* in_sizes, int n_in,
                              void* d_out, int out_size, void* d_ws,
                              size_t ws_size, hipStream_t stream) {
  const float* x = (const float*)d_in[0];
  const float* wqkv = (const float*)d_in[2];
  const float* wo = (const float*)d_in[3];
  char* ws = (char*)d_ws;
  u16* xb = (u16*)(ws);                // 32MB (reused as ao later)
  u16* wqkvb = (u16*)(ws + 33554432);  // 12MB
  u16* wob = (u16*)(ws + 46137344);    // 8MB
  u16* qkv = (u16*)(ws + 54525952);    // 48MB
  u16* vt = (u16*)(ws + 104857600);    // 8MB
  u16* ao = xb;

  k_f32_to_bf16<<<8192, 256, 0, stream>>>(x, xb, 0);
  k_f32_to_bf16<<<3072, 256, 0, stream>>>(wqkv, wqkvb, 4194304L);
  k_f32_to_bf16<<<2048, 256, 0, stream>>>(wo, wob, 0);
  k_gemm256<1><<<384, 512, 0, stream>>>(xb, wqkvb, qkv, M_TOK, QKV_W, D_MODEL);
  k_vtrans<<<dim3(32, 2, 16), 256, 0, stream>>>(qkv, vt);
  k_attn<<<512, 512, 0, stream>>>(qkv, vt, ao);
  k_gemm256<0><<<256, 512, 0, stream>>>(ao, wob, d_out, M_TOK, D_MODEL,
                                        D_MODEL);
}

// Round 8
// 402.195 us; speedup vs baseline: 1.0053x; 1.0053x over previous
//
#include <hip/hip_runtime.h>

#define D_MODEL 2048
#define S_LEN 2048
#define HQ 16
#define HKV 4
#define DH 128
#define QKV_W 3072
#define M_TOK 8192

typedef unsigned short u16;
typedef __bf16 bf16x8 __attribute__((ext_vector_type(8)));
typedef float f32x4 __attribute__((ext_vector_type(4)));
typedef float f32x16 __attribute__((ext_vector_type(16)));

__device__ __forceinline__ u16 f2bf(float f) {
  union { float f; unsigned u; } v; v.f = f;
  unsigned u = v.u;
  return (u16)((u + 0x7fffu + ((u >> 16) & 1u)) >> 16);
}

__device__ __forceinline__ bf16x8 ld_frag(const u16* p) {
  bf16x8 r; __builtin_memcpy(&r, p, 16); return r;
}

__device__ __forceinline__ void gl_lds16(const u16* g, u16* l) {
  __builtin_amdgcn_global_load_lds(
      (const __attribute__((address_space(1))) void*)g,
      (__attribute__((address_space(3))) void*)l, 16, 0, 0);
}

__device__ __forceinline__ unsigned cvtpk(float lo, float hi_) {
  unsigned r;
  asm("v_cvt_pk_bf16_f32 %0, %1, %2" : "=v"(r) : "v"(lo), "v"(hi_));
  return r;
}

__device__ __forceinline__ float exp2a(float x) {
  float r; asm("v_exp_f32 %0, %1" : "=v"(r) : "v"(x)); return r;
}

__device__ __forceinline__ float fmax3(float a, float b, float c) {
  float r;
  asm("v_max3_f32 %0, %1, %2, %3" : "=v"(r) : "v"(a), "v"(b), "v"(c));
  return r;
}

#define MFMA(a, b, c) __builtin_amdgcn_mfma_f32_16x16x32_bf16(a, b, c, 0, 0, 0)
#define MFMA32(a, b, c) __builtin_amdgcn_mfma_f32_32x32x16_bf16(a, b, c, 0, 0, 0)

__device__ __forceinline__ float vmax16(const f32x16& v) {
  float a = fmax3(v[0], v[1], v[2]);
  float b = fmax3(v[3], v[4], v[5]);
  float c = fmax3(v[6], v[7], v[8]);
  float d = fmax3(v[9], v[10], v[11]);
  float e = fmax3(v[12], v[13], v[14]);
  float f_ = fmax3(a, b, v[15]);
  float g = fmax3(c, d, e);
  return fmaxf(f_, g);
}

// ---------------- fp32 -> bf16 convert (optionally scale first scale_n) ----
__global__ __launch_bounds__(256) void k_f32_to_bf16(const float* __restrict__ s,
                                                     u16* __restrict__ d,
                                                     long scale_n) {
  long i = (long)(blockIdx.x * 256 + threadIdx.x) * 8;
  // Q pre-scale: log2(e)/sqrt(128)  (softmax runs in exp2 domain)
  float sc = (i < scale_n) ? 0.12751879677296637f : 1.0f;
  float a[8];
  __builtin_memcpy(a, s + i, 32);
  u16 r[8];
#pragma unroll
  for (int j = 0; j < 8; ++j) r[j] = f2bf(a[j] * sc);
  __builtin_memcpy(d + i, r, 16);
}

// ---------------- 256x256 quad-buffered GEMM  C = A[M,K] * B[N,K]^T --------
template <int OUT_BF16>
__global__ __launch_bounds__(512, 2) void k_gemm256(const u16* __restrict__ A,
                                                    const u16* __restrict__ B,
                                                    void* __restrict__ C,
                                                    int M, int N, int K) {
  __shared__ __attribute__((aligned(16))) u16 As[4][8192];  // 4 x 16KB
  __shared__ __attribute__((aligned(16))) u16 Bs[4][8192];
  const int tid = threadIdx.x;
  const int lane = tid & 63;
  const int wid = tid >> 6;
  const int l15 = lane & 15, l4 = lane >> 4;
  const int wr = wid >> 2, wc = wid & 3;  // 2x4 waves -> 128x64 out each

  const int xcd = blockIdx.x & 7;
  const int slot = blockIdx.x >> 3;
  const long tm = (long)(xcd * 4 + (slot & 3)) * 256;
  const long tn = (long)(slot >> 2) * 256;

  const int cA = l4 ^ ((l15 >> 1) & 3);
  const int arow = wr * 128 + l15;
  const int brow = wc * 64 + l15;

  f32x4 acc[8][4] = {};
  bf16x8 af[4], bfr[4];

#define STG(dst, src, tbase, t_)                                          \
  do {                                                                    \
    _Pragma("unroll") for (int j = 0; j < 2; ++j) {                       \
      int p = tid + j * 512;                                              \
      int row = p >> 2, cc = p & 3;                                       \
      int g = cc ^ ((row >> 1) & 3);                                      \
      gl_lds16(src + (tbase + row) * (long)K + (long)(t_) * 32 + g * 8,   \
               (dst) + p * 8);                                            \
    }                                                                     \
  } while (0)

#define DSR_A(ptr, mh)                                                    \
  _Pragma("unroll") for (int m = 0; m < 4; ++m)                           \
      af[m] = ld_frag((ptr) + (arow + (mh) * 64 + m * 16) * 32 + cA * 8);
#define DSR_B(ptr)                                                        \
  _Pragma("unroll") for (int n = 0; n < 4; ++n)                           \
      bfr[n] = ld_frag((ptr) + (brow + n * 16) * 32 + cA * 8);
#define MM(mh)                                                            \
  _Pragma("unroll") for (int m = 0; m < 4; ++m)                           \
      _Pragma("unroll") for (int n = 0; n < 4; ++n)                       \
          acc[(mh) * 4 + m][n] = MFMA(af[m], bfr[n], acc[(mh) * 4 + m][n]);
#define LGKM0                                              \
  asm volatile("s_waitcnt lgkmcnt(0)" ::: "memory");       \
  __builtin_amdgcn_sched_barrier(0)

  const int NT = K >> 5;  // BK=32
  STG(&As[0][0], A, tm, 0); STG(&Bs[0][0], B, tn, 0);
  STG(&As[1][0], A, tm, 1); STG(&Bs[1][0], B, tn, 1);
  STG(&As[2][0], A, tm, 2); STG(&Bs[2][0], B, tn, 2);
  asm volatile("s_waitcnt vmcnt(8)" ::: "memory");
  __builtin_amdgcn_s_barrier();

  for (int t = 0; t < NT; ++t) {
    const u16* as_ = &As[t & 3][0];
    const u16* bs_ = &Bs[t & 3][0];
    u16* an_ = &As[(t + 3) & 3][0];
    u16* bn_ = &Bs[(t + 3) & 3][0];
    const bool st = (t + 3 < NT);

    DSR_A(as_, 0);
    DSR_B(bs_);
    if (st) STG(an_, A, tm, t + 3);
    __builtin_amdgcn_s_barrier();
    LGKM0;
    __builtin_amdgcn_s_setprio(1); MM(0); __builtin_amdgcn_s_setprio(0);
    __builtin_amdgcn_s_barrier();

    DSR_A(as_, 1);
    if (st) STG(bn_, B, tn, t + 3);
    __builtin_amdgcn_s_barrier();
    LGKM0;
    __builtin_amdgcn_s_setprio(1); MM(1); __builtin_amdgcn_s_setprio(0);
    if (t + 3 < NT) {
      asm volatile("s_waitcnt vmcnt(8)" ::: "memory");
    } else if (t + 2 < NT) {
      asm volatile("s_waitcnt vmcnt(4)" ::: "memory");
    } else if (t + 1 < NT) {
      asm volatile("s_waitcnt vmcnt(0)" ::: "memory");
    }
    __builtin_amdgcn_s_barrier();
  }
#undef STG
#undef DSR_A
#undef DSR_B
#undef MM
#undef LGKM0

#pragma unroll
  for (int m = 0; m < 8; ++m)
#pragma unroll
    for (int n = 0; n < 4; ++n)
#pragma unroll
      for (int i = 0; i < 4; ++i) {
        long row = tm + wr * 128 + m * 16 + l4 * 4 + i;
        long col = tn + wc * 64 + n * 16 + l15;
        if (OUT_BF16)
          ((u16*)C)[row * N + col] = f2bf(acc[m][n][i]);
        else
          ((float*)C)[row * N + col] = acc[m][n][i];
      }
}

// ---------------- V transpose: qkv V-part [s,d] -> vt[b,kv][d][s] ----------
__global__ __launch_bounds__(256) void k_vtrans(const u16* __restrict__ qkv,
                                                u16* __restrict__ vt) {
  __shared__ u16 T[64][68];
  const int tid = threadIdx.x;
  const int st = blockIdx.x;
  const int dt = blockIdx.y;
  const int bh = blockIdx.z;
  const int b = bh >> 2, kvh = bh & 3;
  const long s0 = (long)st * 64, d0 = (long)dt * 64;
#pragma unroll
  for (int j = 0; j < 2; ++j) {
    int chunk = tid + j * 256;
    int row = chunk >> 3, c8 = chunk & 7;
    u16 tmp[8];
    __builtin_memcpy(tmp,
                     qkv + ((long)b * S_LEN + s0 + row) * QKV_W + 2560 +
                         kvh * DH + d0 + c8 * 8,
                     16);
    __builtin_memcpy(&T[row][c8 * 8], tmp, 16);
  }
  __syncthreads();
#pragma unroll
  for (int j = 0; j < 2; ++j) {
    int chunk = tid + j * 256;
    int drow = chunk >> 3, c8 = chunk & 7;
    u16 tmp[8];
#pragma unroll
    for (int e = 0; e < 8; ++e) tmp[e] = T[c8 * 8 + e][drow];
    __builtin_memcpy(vt + ((long)bh * DH + d0 + drow) * S_LEN + s0 + c8 * 8,
                     tmp, 16);
  }
}

// ---------------- flash attention, 8-wave 32x32 swapped-QK^T ---------------
// bkv-major XCD mapping: xcd = bid&7 hosts KV pairs {2*xcd, 2*xcd+1} only
// (2MB KV working set per XCD's L2); 64 blocks/XCD = exactly 2 per CU.
__global__ __launch_bounds__(512, 2) void k_attn(const u16* __restrict__ qkv,
                                                 const u16* __restrict__ vt,
                                                 u16* __restrict__ ao) {
  __shared__ __attribute__((aligned(16))) u16 Ks[2][8192];
  __shared__ __attribute__((aligned(16))) u16 Vs[2][8192];
  const int tid = threadIdx.x;
  const int lane = tid & 63;
  const int wid = tid >> 6;
  const int l31 = lane & 31, hi = lane >> 5;
  const int xcd = blockIdx.x & 7;
  const int s = blockIdx.x >> 3;
  const int bkv = (xcd << 1) | (s & 1);
  const int hh = (s >> 1) & 3;
  const int qt = (s >> 3) & 7;
  const int b = bkv >> 2, kvh = bkv & 3;
  const int h = kvh * 4 + hh;
  const long rowbase = (long)b * S_LEN;
  const int q0 = qt * 256 + wid * 32;
  const long vbase = (long)bkv * DH * S_LEN;

  bf16x8 qf[8];
  {
    const u16* qrow = qkv + (rowbase + q0 + l31) * QKV_W + h * DH;
#pragma unroll
    for (int kk = 0; kk < 8; ++kk) qf[kk] = ld_frag(qrow + kk * 16 + hi * 8);
  }

  bf16x8 onesf;
  {
    union { u16 u[8]; bf16x8 v; } t;
#pragma unroll
    for (int e = 0; e < 8; ++e) t.u[e] = 0x3F80;  // bf16 1.0
    onesf = t.v;
  }

  f32x16 o[4] = {};   // C[d][q], q = l31
  f32x16 osum = {};   // running denominator per q (all regs equal)
  float m_run = -3.0e38f;

#define STAGE(KDST, VDST, tile)                                               \
  do {                                                                        \
    long s0_ = (long)(tile) * 64;                                             \
    _Pragma("unroll") for (int j = 0; j < 2; ++j) {                           \
      int chunk = (wid * 2 + j) * 64 + lane;                                  \
      int row = chunk >> 4, cc = chunk & 15;                                  \
      gl_lds16(qkv + (rowbase + s0_ + row) * QKV_W + 2048 + kvh * DH +        \
                   ((cc ^ (row & 7)) * 8),                                    \
               &(KDST)[chunk * 8]);                                           \
    }                                                                         \
    _Pragma("unroll") for (int j = 0; j < 2; ++j) {                           \
      int chunk = (wid * 2 + j) * 64 + lane;                                  \
      int row = chunk >> 3, cc = chunk & 7;                                   \
      gl_lds16(vt + vbase + (long)row * S_LEN + s0_ + ((cc ^ (row & 7)) * 8), \
               &(VDST)[chunk * 8]);                                           \
    }                                                                         \
  } while (0)

#define PROCESS(KSP, VSP)                                                     \
  {                                                                           \
    f32x16 p0 = {}, p1 = {};                                                  \
    __builtin_amdgcn_s_setprio(1);                                            \
    _Pragma("unroll") for (int kk = 0; kk < 8; ++kk) {                        \
      int ch0 = ((2 * kk + hi) ^ (l31 & 7));                                  \
      int ch1 = ((2 * kk + hi) ^ ((l31 + 32) & 7));                           \
      bf16x8 kf0 = ld_frag((KSP) + l31 * 128 + ch0 * 8);                      \
      bf16x8 kf1 = ld_frag((KSP) + (32 + l31) * 128 + ch1 * 8);               \
      p0 = MFMA32(kf0, qf[kk], p0);                                           \
      p1 = MFMA32(kf1, qf[kk], p1);                                           \
    }                                                                         \
    __builtin_amdgcn_s_setprio(0);                                            \
    float mx = fmaxf(vmax16(p0), vmax16(p1));                                 \
    mx = fmaxf(mx, __shfl_xor(mx, 32, 64));                                   \
    if (__any(mx > m_run + 11.0f)) {                                          \
      float nm = fmaxf(m_run, mx);                                            \
      float alpha = exp2a(m_run - nm);                                        \
      m_run = nm;                                                             \
      _Pragma("unroll") for (int r = 0; r < 16; ++r) osum[r] *= alpha;        \
      _Pragma("unroll") for (int n2 = 0; n2 < 4; ++n2)                        \
          _Pragma("unroll") for (int r = 0; r < 16; ++r) o[n2][r] *= alpha;   \
    }                                                                         \
    _Pragma("unroll") for (int r = 0; r < 16; ++r) {                          \
      p0[r] = exp2a(p0[r] - m_run);                                           \
      p1[r] = exp2a(p1[r] - m_run);                                           \
    }                                                                         \
    __builtin_amdgcn_s_setprio(1);                                            \
    _Pragma("unroll") for (int ks_ = 0; ks_ < 4; ++ks_) {                     \
      const f32x16& pp = (ks_ < 2) ? p0 : p1;                                 \
      const int bb = 8 * (ks_ & 1);                                           \
      unsigned A0 = cvtpk(pp[bb + 0], pp[bb + 1]);                            \
      unsigned A1 = cvtpk(pp[bb + 2], pp[bb + 3]);                            \
      unsigned B0 = cvtpk(pp[bb + 4], pp[bb + 5]);                            \
      unsigned B1 = cvtpk(pp[bb + 6], pp[bb + 7]);                            \
      asm volatile("v_permlane32_swap_b32 %0, %1" : "+v"(A0), "+v"(B0));      \
      asm volatile("v_permlane32_swap_b32 %0, %1" : "+v"(A1), "+v"(B1));      \
      union { unsigned u[4]; bf16x8 v; } pu;                                  \
      pu.u[0] = A0; pu.u[1] = A1; pu.u[2] = B0; pu.u[3] = B1;                 \
      osum = MFMA32(onesf, pu.v, osum);                                       \
      _Pragma("unroll") for (int n2 = 0; n2 < 4; ++n2) {                      \
        int vr = n2 * 32 + l31;                                               \
        int ch = ((2 * ks_ + hi) ^ (vr & 7));                                 \
        bf16x8 vf = ld_frag((VSP) + vr * 64 + ch * 8);                        \
        o[n2] = MFMA32(vf, pu.v, o[n2]);                                      \
      }                                                                       \
    }                                                                         \
    __builtin_amdgcn_s_setprio(0);                                            \
  }

  STAGE(Ks[0], Vs[0], 0);

  for (int kt2 = 0; kt2 < 16; ++kt2) {
    const bool tail = (kt2 == 15);
    // even tile -> buf0 ; prefetch odd tile into buf1
    STAGE(Ks[1], Vs[1], 2 * kt2 + 1);
    asm volatile("s_waitcnt vmcnt(4)" ::: "memory");
    __builtin_amdgcn_s_barrier();
    PROCESS(&Ks[0][0], &Vs[0][0]);
    __builtin_amdgcn_s_barrier();
    // odd tile -> buf1 ; prefetch next even tile into buf0
    if (!tail) {
      STAGE(Ks[0], Vs[0], 2 * kt2 + 2);
      asm volatile("s_waitcnt vmcnt(4)" ::: "memory");
    } else {
      asm volatile("s_waitcnt vmcnt(0)" ::: "memory");
    }
    __builtin_amdgcn_s_barrier();
    PROCESS(&Ks[1][0], &Vs[1][0]);
    __builtin_amdgcn_s_barrier();
  }

  {
    float inv = 1.0f / osum[0];
    u16* orow = ao + (rowbase + q0 + l31) * D_MODEL + h * DH;
#pragma unroll
    for (int n2 = 0; n2 < 4; ++n2)
#pragma unroll
      for (int g = 0; g < 4; ++g) {
        u16 tmp[4];
#pragma unroll
        for (int e = 0; e < 4; ++e) tmp[e] = f2bf(o[n2][g * 4 + e] * inv);
        __builtin_memcpy(orow + n2 * 32 + g * 8 + 4 * hi, tmp, 8);
      }
  }
#undef STAGE
#undef PROCESS
}

// ---------------------------------------------------------------------------
extern "C" void kernel_launch(void* const* d_in, const int* in_sizes, int n_in,
                              void* d_out, int out_size, void* d_ws,
                              size_t ws_size, hipStream_t stream) {
  const float* x = (const float*)d_in[0];
  const float* wqkv = (const float*)d_in[2];
  const float* wo = (const float*)d_in[3];
  char* ws = (char*)d_ws;
  u16* xb = (u16*)(ws);                // 32MB (reused as ao later)
  u16* wqkvb = (u16*)(ws + 33554432);  // 12MB
  u16* wob = (u16*)(ws + 46137344);    // 8MB
  u16* qkv = (u16*)(ws + 54525952);    // 48MB
  u16* vt = (u16*)(ws + 104857600);    // 8MB
  u16* ao = xb;

  k_f32_to_bf16<<<8192, 256, 0, stream>>>(x, xb, 0);
  k_f32_to_bf16<<<3072, 256, 0, stream>>>(wqkv, wqkvb, 4194304L);
  k_f32_to_bf16<<<2048, 256, 0, stream>>>(wo, wob, 0);
  k_gemm256<1><<<384, 512, 0, stream>>>(xb, wqkvb, qkv, M_TOK, QKV_W, D_MODEL);
  k_vtrans<<<dim3(32, 2, 16), 256, 0, stream>>>(qkv, vt);
  k_attn<<<512, 512, 0, stream>>>(qkv, vt, ao);
  k_gemm256<0><<<256, 512, 0, stream>>>(ao, wob, d_out, M_TOK, D_MODEL,
                                        D_MODEL);
}

// Round 9
// 384.865 us; speedup vs baseline: 1.0506x; 1.0450x over previous
//
#include <hip/hip_runtime.h>

#define D_MODEL 2048
#define S_LEN 2048
#define HQ 16
#define HKV 4
#define DH 128
#define QKV_W 3072
#define M_TOK 8192

typedef unsigned short u16;
typedef __bf16 bf16x8 __attribute__((ext_vector_type(8)));
typedef float f32x4 __attribute__((ext_vector_type(4)));
typedef float f32x16 __attribute__((ext_vector_type(16)));

__device__ __forceinline__ u16 f2bf(float f) {
  union { float f; unsigned u; } v; v.f = f;
  unsigned u = v.u;
  return (u16)((u + 0x7fffu + ((u >> 16) & 1u)) >> 16);
}

__device__ __forceinline__ bf16x8 ld_frag(const u16* p) {
  bf16x8 r; __builtin_memcpy(&r, p, 16); return r;
}

__device__ __forceinline__ void gl_lds16(const u16* g, u16* l) {
  __builtin_amdgcn_global_load_lds(
      (const __attribute__((address_space(1))) void*)g,
      (__attribute__((address_space(3))) void*)l, 16, 0, 0);
}

__device__ __forceinline__ unsigned cvtpk(float lo, float hi_) {
  unsigned r;
  asm("v_cvt_pk_bf16_f32 %0, %1, %2" : "=v"(r) : "v"(lo), "v"(hi_));
  return r;
}

__device__ __forceinline__ float exp2a(float x) {
  float r; asm("v_exp_f32 %0, %1" : "=v"(r) : "v"(x)); return r;
}

__device__ __forceinline__ float fmax3(float a, float b, float c) {
  float r;
  asm("v_max3_f32 %0, %1, %2, %3" : "=v"(r) : "v"(a), "v"(b), "v"(c));
  return r;
}

#define MFMA(a, b, c) __builtin_amdgcn_mfma_f32_16x16x32_bf16(a, b, c, 0, 0, 0)
#define MFMA32(a, b, c) __builtin_amdgcn_mfma_f32_32x32x16_bf16(a, b, c, 0, 0, 0)

__device__ __forceinline__ float vmax16(const f32x16& v) {
  float a = fmax3(v[0], v[1], v[2]);
  float b = fmax3(v[3], v[4], v[5]);
  float c = fmax3(v[6], v[7], v[8]);
  float d = fmax3(v[9], v[10], v[11]);
  float e = fmax3(v[12], v[13], v[14]);
  float f_ = fmax3(a, b, v[15]);
  float g = fmax3(c, d, e);
  return fmaxf(f_, g);
}

// ---------------- fp32 -> bf16 convert (optionally scale first scale_n) ----
__global__ __launch_bounds__(256) void k_f32_to_bf16(const float* __restrict__ s,
                                                     u16* __restrict__ d,
                                                     long scale_n) {
  long i = (long)(blockIdx.x * 256 + threadIdx.x) * 8;
  // Q pre-scale: log2(e)/sqrt(128)  (softmax runs in exp2 domain)
  float sc = (i < scale_n) ? 0.12751879677296637f : 1.0f;
  float a[8];
  __builtin_memcpy(a, s + i, 32);
  u16 r[8];
#pragma unroll
  for (int j = 0; j < 8; ++j) r[j] = f2bf(a[j] * sc);
  __builtin_memcpy(d + i, r, 16);
}

// ---------------- 256x128 GEMM  C = A[M,K] * B[N,K]^T  (bf16, f32 acc) -----
// 8 waves of 64x64 (4M x 2N). BK=32, 3 LDS buffers (72KB -> 2 blocks/CU),
// stage tile t+2 during t, gate vmcnt(3) (never 0 until tail).
// Grids are uniform multiples of 256: qkv 768 (3/CU), out 512 (2/CU).
template <int OUT_BF16>
__global__ __launch_bounds__(512, 2) void k_gemm128n(const u16* __restrict__ A,
                                                     const u16* __restrict__ B,
                                                     void* __restrict__ C,
                                                     int M, int N, int K) {
  __shared__ __attribute__((aligned(16))) u16 As[3][8192];  // 256 x 32
  __shared__ __attribute__((aligned(16))) u16 Bs[3][4096];  // 128 x 32
  const int tid = threadIdx.x;
  const int lane = tid & 63;
  const int wid = tid >> 6;
  const int l15 = lane & 15, l4 = lane >> 4;
  const int wr = wid >> 1, wc = wid & 1;  // 4M x 2N waves -> 64x64 out each

  // 2-D XCD rectangle: M always 8192 -> 32 row-tiles = 8 XCDs x 4 stripes.
  const int xcd = blockIdx.x & 7;
  const int slot = blockIdx.x >> 3;
  const long tm = (long)(xcd * 4 + (slot & 3)) * 256;
  const long tn = (long)(slot >> 2) * 128;

  // T2 swizzle: stored chunk g = c ^ ((row>>1)&3); per-thread constant on
  // the read side since row = 16*frag + l15.
  const int cA = l4 ^ ((l15 >> 1) & 3);
  const int arow = wr * 64 + l15;
  const int brow = wc * 64 + l15;

  f32x4 acc[4][4] = {};
  bf16x8 af[4], bfr[4];

#define STGA(buf, t_)                                                     \
  do {                                                                    \
    _Pragma("unroll") for (int j = 0; j < 2; ++j) {                       \
      int p = tid + j * 512;                                              \
      int row = p >> 2, cc = p & 3;                                       \
      int g = cc ^ ((row >> 1) & 3);                                      \
      gl_lds16(A + (tm + row) * (long)K + (long)(t_) * 32 + g * 8,        \
               &As[buf][p * 8]);                                          \
    }                                                                     \
  } while (0)
#define STGB(buf, t_)                                                     \
  do {                                                                    \
    int p = tid;                                                          \
    int row = p >> 2, cc = p & 3;                                         \
    int g = cc ^ ((row >> 1) & 3);                                        \
    gl_lds16(B + (tn + row) * (long)K + (long)(t_) * 32 + g * 8,          \
             &Bs[buf][p * 8]);                                            \
  } while (0)

#define DSR(buf)                                                          \
  _Pragma("unroll") for (int m = 0; m < 4; ++m)                           \
      af[m] = ld_frag(&As[buf][(arow + m * 16) * 32 + cA * 8]);           \
  _Pragma("unroll") for (int n = 0; n < 4; ++n)                           \
      bfr[n] = ld_frag(&Bs[buf][(brow + n * 16) * 32 + cA * 8]);
#define MM16                                                              \
  _Pragma("unroll") for (int m = 0; m < 4; ++m)                           \
      _Pragma("unroll") for (int n = 0; n < 4; ++n)                       \
          acc[m][n] = MFMA(af[m], bfr[n], acc[m][n]);
#define LGKM0                                              \
  asm volatile("s_waitcnt lgkmcnt(0)" ::: "memory");       \
  __builtin_amdgcn_sched_barrier(0)

  const int NT = K >> 5;  // BK=32
  // prologue: stage tiles 0,1 (3 loads/thread each); gate tile 0
  STGA(0, 0); STGB(0, 0);
  STGA(1, 1); STGB(1, 1);
  asm volatile("s_waitcnt vmcnt(3)" ::: "memory");
  __builtin_amdgcn_s_barrier();

  for (int t = 0; t < NT; ++t) {
    const int b0 = t % 3;
    const int b2 = (t + 2) % 3;

    DSR(b0);
    if (t + 2 < NT) { STGA(b2, t + 2); STGB(b2, t + 2); }
    __builtin_amdgcn_s_barrier();
    LGKM0;
    __builtin_amdgcn_s_setprio(1); MM16; __builtin_amdgcn_s_setprio(0);
    // gate tile t+1 (staged at t-1); keep t+2's 3 loads in flight
    if (t + 2 < NT) {
      asm volatile("s_waitcnt vmcnt(3)" ::: "memory");
    } else if (t + 1 < NT) {
      asm volatile("s_waitcnt vmcnt(0)" ::: "memory");
    }
    __builtin_amdgcn_s_barrier();
  }
#undef STGA
#undef STGB
#undef DSR
#undef MM16
#undef LGKM0

#pragma unroll
  for (int m = 0; m < 4; ++m)
#pragma unroll
    for (int n = 0; n < 4; ++n)
#pragma unroll
      for (int i = 0; i < 4; ++i) {
        long row = tm + wr * 64 + m * 16 + l4 * 4 + i;
        long col = tn + wc * 64 + n * 16 + l15;
        if (OUT_BF16)
          ((u16*)C)[row * N + col] = f2bf(acc[m][n][i]);
        else
          ((float*)C)[row * N + col] = acc[m][n][i];
      }
}

// ---------------- V transpose: qkv V-part [s,d] -> vt[b,kv][d][s] ----------
__global__ __launch_bounds__(256) void k_vtrans(const u16* __restrict__ qkv,
                                                u16* __restrict__ vt) {
  __shared__ u16 T[64][68];
  const int tid = threadIdx.x;
  const int st = blockIdx.x;
  const int dt = blockIdx.y;
  const int bh = blockIdx.z;
  const int b = bh >> 2, kvh = bh & 3;
  const long s0 = (long)st * 64, d0 = (long)dt * 64;
#pragma unroll
  for (int j = 0; j < 2; ++j) {
    int chunk = tid + j * 256;
    int row = chunk >> 3, c8 = chunk & 7;
    u16 tmp[8];
    __builtin_memcpy(tmp,
                     qkv + ((long)b * S_LEN + s0 + row) * QKV_W + 2560 +
                         kvh * DH + d0 + c8 * 8,
                     16);
    __builtin_memcpy(&T[row][c8 * 8], tmp, 16);
  }
  __syncthreads();
#pragma unroll
  for (int j = 0; j < 2; ++j) {
    int chunk = tid + j * 256;
    int drow = chunk >> 3, c8 = chunk & 7;
    u16 tmp[8];
#pragma unroll
    for (int e = 0; e < 8; ++e) tmp[e] = T[c8 * 8 + e][drow];
    __builtin_memcpy(vt + ((long)bh * DH + d0 + drow) * S_LEN + s0 + c8 * 8,
                     tmp, 16);
  }
}

// ---------------- flash attention, 8-wave 32x32 swapped-QK^T ---------------
// bkv-major XCD mapping: xcd = bid&7 hosts KV pairs {2*xcd, 2*xcd+1} only
// (2MB KV working set per XCD's L2); 64 blocks/XCD = exactly 2 per CU.
__global__ __launch_bounds__(512, 2) void k_attn(const u16* __restrict__ qkv,
                                                 const u16* __restrict__ vt,
                                                 u16* __restrict__ ao) {
  __shared__ __attribute__((aligned(16))) u16 Ks[2][8192];
  __shared__ __attribute__((aligned(16))) u16 Vs[2][8192];
  const int tid = threadIdx.x;
  const int lane = tid & 63;
  const int wid = tid >> 6;
  const int l31 = lane & 31, hi = lane >> 5;
  const int xcd = blockIdx.x & 7;
  const int s = blockIdx.x >> 3;
  const int bkv = (xcd << 1) | (s & 1);
  const int hh = (s >> 1) & 3;
  const int qt = (s >> 3) & 7;
  const int b = bkv >> 2, kvh = bkv & 3;
  const int h = kvh * 4 + hh;
  const long rowbase = (long)b * S_LEN;
  const int q0 = qt * 256 + wid * 32;
  const long vbase = (long)bkv * DH * S_LEN;

  bf16x8 qf[8];
  {
    const u16* qrow = qkv + (rowbase + q0 + l31) * QKV_W + h * DH;
#pragma unroll
    for (int kk = 0; kk < 8; ++kk) qf[kk] = ld_frag(qrow + kk * 16 + hi * 8);
  }

  bf16x8 onesf;
  {
    union { u16 u[8]; bf16x8 v; } t;
#pragma unroll
    for (int e = 0; e < 8; ++e) t.u[e] = 0x3F80;  // bf16 1.0
    onesf = t.v;
  }

  f32x16 o[4] = {};   // C[d][q], q = l31
  f32x16 osum = {};   // running denominator per q (all regs equal)
  float m_run = -3.0e38f;

#define STAGE(KDST, VDST, tile)                                               \
  do {                                                                        \
    long s0_ = (long)(tile) * 64;                                             \
    _Pragma("unroll") for (int j = 0; j < 2; ++j) {                           \
      int chunk = (wid * 2 + j) * 64 + lane;                                  \
      int row = chunk >> 4, cc = chunk & 15;                                  \
      gl_lds16(qkv + (rowbase + s0_ + row) * QKV_W + 2048 + kvh * DH +        \
                   ((cc ^ (row & 7)) * 8),                                    \
               &(KDST)[chunk * 8]);                                           \
    }                                                                         \
    _Pragma("unroll") for (int j = 0; j < 2; ++j) {                           \
      int chunk = (wid * 2 + j) * 64 + lane;                                  \
      int row = chunk >> 3, cc = chunk & 7;                                   \
      gl_lds16(vt + vbase + (long)row * S_LEN + s0_ + ((cc ^ (row & 7)) * 8), \
               &(VDST)[chunk * 8]);                                           \
    }                                                                         \
  } while (0)

#define PROCESS(KSP, VSP)                                                     \
  {                                                                           \
    f32x16 p0 = {}, p1 = {};                                                  \
    __builtin_amdgcn_s_setprio(1);                                            \
    _Pragma("unroll") for (int kk = 0; kk < 8; ++kk) {                        \
      int ch0 = ((2 * kk + hi) ^ (l31 & 7));                                  \
      int ch1 = ((2 * kk + hi) ^ ((l31 + 32) & 7));                           \
      bf16x8 kf0 = ld_frag((KSP) + l31 * 128 + ch0 * 8);                      \
      bf16x8 kf1 = ld_frag((KSP) + (32 + l31) * 128 + ch1 * 8);               \
      p0 = MFMA32(kf0, qf[kk], p0);                                           \
      p1 = MFMA32(kf1, qf[kk], p1);                                           \
    }                                                                         \
    __builtin_amdgcn_s_setprio(0);                                            \
    float mx = fmaxf(vmax16(p0), vmax16(p1));                                 \
    mx = fmaxf(mx, __shfl_xor(mx, 32, 64));                                   \
    if (__any(mx > m_run + 11.0f)) {                                          \
      float nm = fmaxf(m_run, mx);                                            \
      float alpha = exp2a(m_run - nm);                                        \
      m_run = nm;                                                             \
      _Pragma("unroll") for (int r = 0; r < 16; ++r) osum[r] *= alpha;        \
      _Pragma("unroll") for (int n2 = 0; n2 < 4; ++n2)                        \
          _Pragma("unroll") for (int r = 0; r < 16; ++r) o[n2][r] *= alpha;   \
    }                                                                         \
    _Pragma("unroll") for (int r = 0; r < 16; ++r) {                          \
      p0[r] = exp2a(p0[r] - m_run);                                           \
      p1[r] = exp2a(p1[r] - m_run);                                           \
    }                                                                         \
    __builtin_amdgcn_s_setprio(1);                                            \
    _Pragma("unroll") for (int ks_ = 0; ks_ < 4; ++ks_) {                     \
      const f32x16& pp = (ks_ < 2) ? p0 : p1;                                 \
      const int bb = 8 * (ks_ & 1);                                           \
      unsigned A0 = cvtpk(pp[bb + 0], pp[bb + 1]);                            \
      unsigned A1 = cvtpk(pp[bb + 2], pp[bb + 3]);                            \
      unsigned B0 = cvtpk(pp[bb + 4], pp[bb + 5]);                            \
      unsigned B1 = cvtpk(pp[bb + 6], pp[bb + 7]);                            \
      asm volatile("v_permlane32_swap_b32 %0, %1" : "+v"(A0), "+v"(B0));      \
      asm volatile("v_permlane32_swap_b32 %0, %1" : "+v"(A1), "+v"(B1));      \
      union { unsigned u[4]; bf16x8 v; } pu;                                  \
      pu.u[0] = A0; pu.u[1] = A1; pu.u[2] = B0; pu.u[3] = B1;                 \
      osum = MFMA32(onesf, pu.v, osum);                                       \
      _Pragma("unroll") for (int n2 = 0; n2 < 4; ++n2) {                      \
        int vr = n2 * 32 + l31;                                               \
        int ch = ((2 * ks_ + hi) ^ (vr & 7));                                 \
        bf16x8 vf = ld_frag((VSP) + vr * 64 + ch * 8);                        \
        o[n2] = MFMA32(vf, pu.v, o[n2]);                                      \
      }                                                                       \
    }                                                                         \
    __builtin_amdgcn_s_setprio(0);                                            \
  }

  STAGE(Ks[0], Vs[0], 0);

  for (int kt2 = 0; kt2 < 16; ++kt2) {
    const bool tail = (kt2 == 15);
    // even tile -> buf0 ; prefetch odd tile into buf1
    STAGE(Ks[1], Vs[1], 2 * kt2 + 1);
    asm volatile("s_waitcnt vmcnt(4)" ::: "memory");
    __builtin_amdgcn_s_barrier();
    PROCESS(&Ks[0][0], &Vs[0][0]);
    __builtin_amdgcn_s_barrier();
    // odd tile -> buf1 ; prefetch next even tile into buf0
    if (!tail) {
      STAGE(Ks[0], Vs[0], 2 * kt2 + 2);
      asm volatile("s_waitcnt vmcnt(4)" ::: "memory");
    } else {
      asm volatile("s_waitcnt vmcnt(0)" ::: "memory");
    }
    __builtin_amdgcn_s_barrier();
    PROCESS(&Ks[1][0], &Vs[1][0]);
    __builtin_amdgcn_s_barrier();
  }

  {
    float inv = 1.0f / osum[0];
    u16* orow = ao + (rowbase + q0 + l31) * D_MODEL + h * DH;
#pragma unroll
    for (int n2 = 0; n2 < 4; ++n2)
#pragma unroll
      for (int g = 0; g < 4; ++g) {
        u16 tmp[4];
#pragma unroll
        for (int e = 0; e < 4; ++e) tmp[e] = f2bf(o[n2][g * 4 + e] * inv);
        __builtin_memcpy(orow + n2 * 32 + g * 8 + 4 * hi, tmp, 8);
      }
  }
#undef STAGE
#undef PROCESS
}

// ---------------------------------------------------------------------------
extern "C" void kernel_launch(void* const* d_in, const int* in_sizes, int n_in,
                              void* d_out, int out_size, void* d_ws,
                              size_t ws_size, hipStream_t stream) {
  const float* x = (const float*)d_in[0];
  const float* wqkv = (const float*)d_in[2];
  const float* wo = (const float*)d_in[3];
  char* ws = (char*)d_ws;
  u16* xb = (u16*)(ws);                // 32MB (reused as ao later)
  u16* wqkvb = (u16*)(ws + 33554432);  // 12MB
  u16* wob = (u16*)(ws + 46137344);    // 8MB
  u16* qkv = (u16*)(ws + 54525952);    // 48MB
  u16* vt = (u16*)(ws + 104857600);    // 8MB
  u16* ao = xb;

  k_f32_to_bf16<<<8192, 256, 0, stream>>>(x, xb, 0);
  k_f32_to_bf16<<<3072, 256, 0, stream>>>(wqkv, wqkvb, 4194304L);
  k_f32_to_bf16<<<2048, 256, 0, stream>>>(wo, wob, 0);
  k_gemm128n<1><<<768, 512, 0, stream>>>(xb, wqkvb, qkv, M_TOK, QKV_W,
                                         D_MODEL);
  k_vtrans<<<dim3(32, 2, 16), 256, 0, stream>>>(qkv, vt);
  k_attn<<<512, 512, 0, stream>>>(qkv, vt, ao);
  k_gemm128n<0><<<512, 512, 0, stream>>>(ao, wob, d_out, M_TOK, D_MODEL,
                                         D_MODEL);
}

// Round 10
// 373.084 us; speedup vs baseline: 1.0837x; 1.0316x over previous
//
#include <hip/hip_runtime.h>

#define D_MODEL 2048
#define S_LEN 2048
#define HQ 16
#define HKV 4
#define DH 128
#define QKV_W 3072
#define M_TOK 8192

typedef unsigned short u16;
typedef __bf16 bf16x8 __attribute__((ext_vector_type(8)));
typedef float f32x4 __attribute__((ext_vector_type(4)));
typedef float f32x16 __attribute__((ext_vector_type(16)));

__device__ __forceinline__ u16 f2bf(float f) {
  union { float f; unsigned u; } v; v.f = f;
  unsigned u = v.u;
  return (u16)((u + 0x7fffu + ((u >> 16) & 1u)) >> 16);
}

__device__ __forceinline__ bf16x8 ld_frag(const u16* p) {
  bf16x8 r; __builtin_memcpy(&r, p, 16); return r;
}

__device__ __forceinline__ void gl_lds16(const u16* g, u16* l) {
  __builtin_amdgcn_global_load_lds(
      (const __attribute__((address_space(1))) void*)g,
      (__attribute__((address_space(3))) void*)l, 16, 0, 0);
}

__device__ __forceinline__ unsigned cvtpk(float lo, float hi_) {
  unsigned r;
  asm("v_cvt_pk_bf16_f32 %0, %1, %2" : "=v"(r) : "v"(lo), "v"(hi_));
  return r;
}

__device__ __forceinline__ float exp2a(float x) {
  float r; asm("v_exp_f32 %0, %1" : "=v"(r) : "v"(x)); return r;
}

__device__ __forceinline__ float fmax3(float a, float b, float c) {
  float r;
  asm("v_max3_f32 %0, %1, %2, %3" : "=v"(r) : "v"(a), "v"(b), "v"(c));
  return r;
}

#define MFMA(a, b, c) __builtin_amdgcn_mfma_f32_16x16x32_bf16(a, b, c, 0, 0, 0)
#define MFMA32(a, b, c) __builtin_amdgcn_mfma_f32_32x32x16_bf16(a, b, c, 0, 0, 0)

__device__ __forceinline__ float vmax16(const f32x16& v) {
  float a = fmax3(v[0], v[1], v[2]);
  float b = fmax3(v[3], v[4], v[5]);
  float c = fmax3(v[6], v[7], v[8]);
  float d = fmax3(v[9], v[10], v[11]);
  float e = fmax3(v[12], v[13], v[14]);
  float f_ = fmax3(a, b, v[15]);
  float g = fmax3(c, d, e);
  return fmaxf(f_, g);
}

// ---------------- fp32 -> bf16 convert (optionally scale first scale_n) ----
__global__ __launch_bounds__(256) void k_f32_to_bf16(const float* __restrict__ s,
                                                     u16* __restrict__ d,
                                                     long scale_n) {
  long i = (long)(blockIdx.x * 256 + threadIdx.x) * 8;
  // Q pre-scale: log2(e)/sqrt(128)  (softmax runs in exp2 domain)
  float sc = (i < scale_n) ? 0.12751879677296637f : 1.0f;
  float a[8];
  __builtin_memcpy(a, s + i, 32);
  u16 r[8];
#pragma unroll
  for (int j = 0; j < 8; ++j) r[j] = f2bf(a[j] * sc);
  __builtin_memcpy(d + i, r, 16);
}

// ---------------- 256x256 8-phase GEMM  C = A[M,K] * B[N,K]^T --------------
// m201-style: BK=64 = 2 ksteps; 8 waves (2Mx4N), per-wave out 128x64.
// Per K-tile group: 4 phases x {ds_read (12|4); stage 1 half-tile; bar;
// lgkm0; setprio 16 MFMA; bar}. B-frags cached in regs for the whole group.
// Stage stream: A0(g+1)@p1, A1(g+1)@p2, B0(g+2)@p3, B1(g+2)@p4; single
// vmcnt(4) gate per group (drains A(g+1)+B(g+1), keeps B(g+2) in flight).
// LDS 128KB dynamic: S[2 buf][4 slot: A0,A1,B0,B1][8192 u16].
template <int OUT_BF16>
__global__ __launch_bounds__(512, 2) void k_gemm8p(const u16* __restrict__ A,
                                                   const u16* __restrict__ B,
                                                   void* __restrict__ C,
                                                   int M, int N, int K) {
  extern __shared__ __attribute__((aligned(16))) u16 S[];
  const int tid = threadIdx.x;
  const int lane = tid & 63;
  const int wid = tid >> 6;
  const int l15 = lane & 15, l4 = lane >> 4;
  const int wr = wid >> 2, wc = wid & 3;  // 2M x 4N waves

  // 2-D XCD rectangle: M=8192 -> 32 row-tiles = 8 XCDs x 4 stripes.
  const int xcd = blockIdx.x & 7;
  const int slot = blockIdx.x >> 3;
  const long tm = (long)(xcd * 4 + (slot & 3)) * 256;
  const long tn = (long)(slot >> 2) * 256;

  f32x4 acc[8][4] = {};
  bf16x8 af[4], bfr[8];

  // stage one half-tile (128 rows x 64 K) of tile g, slot sl (0=A0,1=A1,2=B0,3=B1)
#define STG_HT(g, sl)                                                       \
  do {                                                                      \
    const u16* src_ = ((sl) < 2) ? A : B;                                   \
    long rb_ = ((sl) < 2) ? (tm + (sl) * 128) : (tn + ((sl) - 2) * 128);    \
    u16* dst_ = S + (((g) & 1) * 4 + (sl)) * 8192;                          \
    _Pragma("unroll") for (int j = 0; j < 2; ++j) {                         \
      int q = tid + j * 512;                                                \
      int row = q >> 3, c = q & 7;                                          \
      int gg = c ^ (row & 7);                                               \
      gl_lds16(src_ + (rb_ + row) * (long)K + (long)(g) * 64 + gg * 8,      \
               dst_ + q * 8);                                               \
    }                                                                       \
  } while (0)

#define DSR_B(g)                                                            \
  {                                                                         \
    const u16* bs_ = S + (((g) & 1) * 4 + 2 + (wc >> 1)) * 8192 +           \
                     ((wc & 1) * 64) * 64;                                  \
    _Pragma("unroll") for (int n = 0; n < 4; ++n)                           \
        _Pragma("unroll") for (int k = 0; k < 2; ++k)                       \
            bfr[n * 2 + k] = ld_frag(bs_ + (n * 16 + l15) * 64 +            \
                                     (((k * 4 + l4) ^ (l15 & 7)) * 8));     \
  }
#define DSR_A(g, mp)                                                        \
  {                                                                         \
    const u16* as_ = S + (((g) & 1) * 4 + wr) * 8192;                       \
    _Pragma("unroll") for (int m = 0; m < 2; ++m)                           \
        _Pragma("unroll") for (int k = 0; k < 2; ++k)                       \
            af[m * 2 + k] = ld_frag(as_ + (((mp) * 2 + m) * 16 + l15) * 64 +\
                                    (((k * 4 + l4) ^ (l15 & 7)) * 8));      \
  }
#define MMQ(mp)                                                             \
  _Pragma("unroll") for (int m = 0; m < 2; ++m)                             \
      _Pragma("unroll") for (int n = 0; n < 4; ++n)                         \
          _Pragma("unroll") for (int k = 0; k < 2; ++k)                     \
              acc[(mp) * 2 + m][n] =                                        \
                  MFMA(af[m * 2 + k], bfr[n * 2 + k], acc[(mp) * 2 + m][n]);
#define LGKM0                                              \
  asm volatile("s_waitcnt lgkmcnt(0)" ::: "memory");       \
  __builtin_amdgcn_sched_barrier(0)
#define PRIO1 __builtin_amdgcn_s_setprio(1)
#define PRIO0 __builtin_amdgcn_s_setprio(0)
#define BAR __builtin_amdgcn_s_barrier()

  const int NT = K >> 6;  // BK=64
  // prologue: A0(0) A1(0) B0(0) B1(0) B0(1) B1(1); gate drains tile 0
  STG_HT(0, 0); STG_HT(0, 1); STG_HT(0, 2); STG_HT(0, 3);
  STG_HT(1, 2); STG_HT(1, 3);
  asm volatile("s_waitcnt vmcnt(4)" ::: "memory");
  BAR;

  for (int g = 0; g < NT; ++g) {
    const bool s1 = (g + 1 < NT), s2 = (g + 2 < NT);
    // phase 1: B (8 reads) + A m01; stage A0(g+1)
    DSR_B(g); DSR_A(g, 0);
    if (s1) STG_HT(g + 1, 0);
    BAR;
    LGKM0;
    PRIO1; MMQ(0); PRIO0;
    BAR;
    // phase 2: A m23; stage A1(g+1)
    DSR_A(g, 1);
    if (s1) STG_HT(g + 1, 1);
    BAR;
    LGKM0;
    PRIO1; MMQ(1); PRIO0;
    BAR;
    // phase 3: A m45; stage B0(g+2)
    DSR_A(g, 2);
    if (s2) STG_HT(g + 2, 2);
    BAR;
    LGKM0;
    PRIO1; MMQ(2); PRIO0;
    BAR;
    // phase 4: A m67; stage B1(g+2); counted gate
    DSR_A(g, 3);
    if (s2) STG_HT(g + 2, 3);
    BAR;
    LGKM0;
    PRIO1; MMQ(3); PRIO0;
    if (s2) {
      asm volatile("s_waitcnt vmcnt(4)" ::: "memory");
    } else if (s1) {
      asm volatile("s_waitcnt vmcnt(0)" ::: "memory");
    }
    BAR;
  }
#undef STG_HT
#undef DSR_B
#undef DSR_A
#undef MMQ
#undef LGKM0
#undef PRIO1
#undef PRIO0
#undef BAR

#pragma unroll
  for (int mf = 0; mf < 8; ++mf)
#pragma unroll
    for (int n = 0; n < 4; ++n)
#pragma unroll
      for (int i = 0; i < 4; ++i) {
        long row = tm + wr * 128 + mf * 16 + l4 * 4 + i;
        long col = tn + wc * 64 + n * 16 + l15;
        if (OUT_BF16)
          ((u16*)C)[row * N + col] = f2bf(acc[mf][n][i]);
        else
          ((float*)C)[row * N + col] = acc[mf][n][i];
      }
}

// ---------------- V transpose: qkv V-part [s,d] -> vt[b,kv][d][s] ----------
__global__ __launch_bounds__(256) void k_vtrans(const u16* __restrict__ qkv,
                                                u16* __restrict__ vt) {
  __shared__ u16 T[64][68];
  const int tid = threadIdx.x;
  const int st = blockIdx.x;
  const int dt = blockIdx.y;
  const int bh = blockIdx.z;
  const int b = bh >> 2, kvh = bh & 3;
  const long s0 = (long)st * 64, d0 = (long)dt * 64;
#pragma unroll
  for (int j = 0; j < 2; ++j) {
    int chunk = tid + j * 256;
    int row = chunk >> 3, c8 = chunk & 7;
    u16 tmp[8];
    __builtin_memcpy(tmp,
                     qkv + ((long)b * S_LEN + s0 + row) * QKV_W + 2560 +
                         kvh * DH + d0 + c8 * 8,
                     16);
    __builtin_memcpy(&T[row][c8 * 8], tmp, 16);
  }
  __syncthreads();
#pragma unroll
  for (int j = 0; j < 2; ++j) {
    int chunk = tid + j * 256;
    int drow = chunk >> 3, c8 = chunk & 7;
    u16 tmp[8];
#pragma unroll
    for (int e = 0; e < 8; ++e) tmp[e] = T[c8 * 8 + e][drow];
    __builtin_memcpy(vt + ((long)bh * DH + d0 + drow) * S_LEN + s0 + c8 * 8,
                     tmp, 16);
  }
}

// ---------------- flash attention, 8-wave 32x32 swapped-QK^T ---------------
// bkv-major XCD mapping: xcd = bid&7 hosts KV pairs {2*xcd, 2*xcd+1} only
// (2MB KV working set per XCD's L2); 64 blocks/XCD = exactly 2 per CU.
__global__ __launch_bounds__(512, 2) void k_attn(const u16* __restrict__ qkv,
                                                 const u16* __restrict__ vt,
                                                 u16* __restrict__ ao) {
  __shared__ __attribute__((aligned(16))) u16 Ks[2][8192];
  __shared__ __attribute__((aligned(16))) u16 Vs[2][8192];
  const int tid = threadIdx.x;
  const int lane = tid & 63;
  const int wid = tid >> 6;
  const int l31 = lane & 31, hi = lane >> 5;
  const int xcd = blockIdx.x & 7;
  const int s = blockIdx.x >> 3;
  const int bkv = (xcd << 1) | (s & 1);
  const int hh = (s >> 1) & 3;
  const int qt = (s >> 3) & 7;
  const int b = bkv >> 2, kvh = bkv & 3;
  const int h = kvh * 4 + hh;
  const long rowbase = (long)b * S_LEN;
  const int q0 = qt * 256 + wid * 32;
  const long vbase = (long)bkv * DH * S_LEN;

  bf16x8 qf[8];
  {
    const u16* qrow = qkv + (rowbase + q0 + l31) * QKV_W + h * DH;
#pragma unroll
    for (int kk = 0; kk < 8; ++kk) qf[kk] = ld_frag(qrow + kk * 16 + hi * 8);
  }

  bf16x8 onesf;
  {
    union { u16 u[8]; bf16x8 v; } t;
#pragma unroll
    for (int e = 0; e < 8; ++e) t.u[e] = 0x3F80;  // bf16 1.0
    onesf = t.v;
  }

  f32x16 o[4] = {};   // C[d][q], q = l31
  f32x16 osum = {};   // running denominator per q (all regs equal)
  float m_run = -3.0e38f;

#define STAGE(KDST, VDST, tile)                                               \
  do {                                                                        \
    long s0_ = (long)(tile) * 64;                                             \
    _Pragma("unroll") for (int j = 0; j < 2; ++j) {                           \
      int chunk = (wid * 2 + j) * 64 + lane;                                  \
      int row = chunk >> 4, cc = chunk & 15;                                  \
      gl_lds16(qkv + (rowbase + s0_ + row) * QKV_W + 2048 + kvh * DH +        \
                   ((cc ^ (row & 7)) * 8),                                    \
               &(KDST)[chunk * 8]);                                           \
    }                                                                         \
    _Pragma("unroll") for (int j = 0; j < 2; ++j) {                           \
      int chunk = (wid * 2 + j) * 64 + lane;                                  \
      int row = chunk >> 3, cc = chunk & 7;                                   \
      gl_lds16(vt + vbase + (long)row * S_LEN + s0_ + ((cc ^ (row & 7)) * 8), \
               &(VDST)[chunk * 8]);                                           \
    }                                                                         \
  } while (0)

#define PROCESS(KSP, VSP)                                                     \
  {                                                                           \
    f32x16 p0 = {}, p1 = {};                                                  \
    __builtin_amdgcn_s_setprio(1);                                            \
    _Pragma("unroll") for (int kk = 0; kk < 8; ++kk) {                        \
      int ch0 = ((2 * kk + hi) ^ (l31 & 7));                                  \
      int ch1 = ((2 * kk + hi) ^ ((l31 + 32) & 7));                           \
      bf16x8 kf0 = ld_frag((KSP) + l31 * 128 + ch0 * 8);                      \
      bf16x8 kf1 = ld_frag((KSP) + (32 + l31) * 128 + ch1 * 8);               \
      p0 = MFMA32(kf0, qf[kk], p0);                                           \
      p1 = MFMA32(kf1, qf[kk], p1);                                           \
    }                                                                         \
    __builtin_amdgcn_s_setprio(0);                                            \
    float mx = fmaxf(vmax16(p0), vmax16(p1));                                 \
    mx = fmaxf(mx, __shfl_xor(mx, 32, 64));                                   \
    if (__any(mx > m_run + 11.0f)) {                                          \
      float nm = fmaxf(m_run, mx);                                            \
      float alpha = exp2a(m_run - nm);                                        \
      m_run = nm;                                                             \
      _Pragma("unroll") for (int r = 0; r < 16; ++r) osum[r] *= alpha;        \
      _Pragma("unroll") for (int n2 = 0; n2 < 4; ++n2)                        \
          _Pragma("unroll") for (int r = 0; r < 16; ++r) o[n2][r] *= alpha;   \
    }                                                                         \
    _Pragma("unroll") for (int r = 0; r < 16; ++r) {                          \
      p0[r] = exp2a(p0[r] - m_run);                                           \
      p1[r] = exp2a(p1[r] - m_run);                                           \
    }                                                                         \
    __builtin_amdgcn_s_setprio(1);                                            \
    _Pragma("unroll") for (int ks_ = 0; ks_ < 4; ++ks_) {                     \
      const f32x16& pp = (ks_ < 2) ? p0 : p1;                                 \
      const int bb = 8 * (ks_ & 1);                                           \
      unsigned A0 = cvtpk(pp[bb + 0], pp[bb + 1]);                            \
      unsigned A1 = cvtpk(pp[bb + 2], pp[bb + 3]);                            \
      unsigned B0 = cvtpk(pp[bb + 4], pp[bb + 5]);                            \
      unsigned B1 = cvtpk(pp[bb + 6], pp[bb + 7]);                            \
      asm volatile("v_permlane32_swap_b32 %0, %1" : "+v"(A0), "+v"(B0));      \
      asm volatile("v_permlane32_swap_b32 %0, %1" : "+v"(A1), "+v"(B1));      \
      union { unsigned u[4]; bf16x8 v; } pu;                                  \
      pu.u[0] = A0; pu.u[1] = A1; pu.u[2] = B0; pu.u[3] = B1;                 \
      osum = MFMA32(onesf, pu.v, osum);                                       \
      _Pragma("unroll") for (int n2 = 0; n2 < 4; ++n2) {                      \
        int vr = n2 * 32 + l31;                                               \
        int ch = ((2 * ks_ + hi) ^ (vr & 7));                                 \
        bf16x8 vf = ld_frag((VSP) + vr * 64 + ch * 8);                        \
        o[n2] = MFMA32(vf, pu.v, o[n2]);                                      \
      }                                                                       \
    }                                                                         \
    __builtin_amdgcn_s_setprio(0);                                            \
  }

  STAGE(Ks[0], Vs[0], 0);

  for (int kt2 = 0; kt2 < 16; ++kt2) {
    const bool tail = (kt2 == 15);
    // even tile -> buf0 ; prefetch odd tile into buf1
    STAGE(Ks[1], Vs[1], 2 * kt2 + 1);
    asm volatile("s_waitcnt vmcnt(4)" ::: "memory");
    __builtin_amdgcn_s_barrier();
    PROCESS(&Ks[0][0], &Vs[0][0]);
    __builtin_amdgcn_s_barrier();
    // odd tile -> buf1 ; prefetch next even tile into buf0
    if (!tail) {
      STAGE(Ks[0], Vs[0], 2 * kt2 + 2);
      asm volatile("s_waitcnt vmcnt(4)" ::: "memory");
    } else {
      asm volatile("s_waitcnt vmcnt(0)" ::: "memory");
    }
    __builtin_amdgcn_s_barrier();
    PROCESS(&Ks[1][0], &Vs[1][0]);
    __builtin_amdgcn_s_barrier();
  }

  {
    float inv = 1.0f / osum[0];
    u16* orow = ao + (rowbase + q0 + l31) * D_MODEL + h * DH;
#pragma unroll
    for (int n2 = 0; n2 < 4; ++n2)
#pragma unroll
      for (int g = 0; g < 4; ++g) {
        u16 tmp[4];
#pragma unroll
        for (int e = 0; e < 4; ++e) tmp[e] = f2bf(o[n2][g * 4 + e] * inv);
        __builtin_memcpy(orow + n2 * 32 + g * 8 + 4 * hi, tmp, 8);
      }
  }
#undef STAGE
#undef PROCESS
}

// ---------------------------------------------------------------------------
extern "C" void kernel_launch(void* const* d_in, const int* in_sizes, int n_in,
                              void* d_out, int out_size, void* d_ws,
                              size_t ws_size, hipStream_t stream) {
  const float* x = (const float*)d_in[0];
  const float* wqkv = (const float*)d_in[2];
  const float* wo = (const float*)d_in[3];
  char* ws = (char*)d_ws;
  u16* xb = (u16*)(ws);                // 32MB (reused as ao later)
  u16* wqkvb = (u16*)(ws + 33554432);  // 12MB
  u16* wob = (u16*)(ws + 46137344);    // 8MB
  u16* qkv = (u16*)(ws + 54525952);    // 48MB
  u16* vt = (u16*)(ws + 104857600);    // 8MB
  u16* ao = xb;

  // allow 128KB dynamic LDS for the 8-phase GEMMs (idempotent host calls)
  hipFuncSetAttribute(reinterpret_cast<const void*>(k_gemm8p<1>),
                      hipFuncAttributeMaxDynamicSharedMemorySize, 131072);
  hipFuncSetAttribute(reinterpret_cast<const void*>(k_gemm8p<0>),
                      hipFuncAttributeMaxDynamicSharedMemorySize, 131072);

  k_f32_to_bf16<<<8192, 256, 0, stream>>>(x, xb, 0);
  k_f32_to_bf16<<<3072, 256, 0, stream>>>(wqkv, wqkvb, 4194304L);
  k_f32_to_bf16<<<2048, 256, 0, stream>>>(wo, wob, 0);
  k_gemm8p<1><<<384, 512, 131072, stream>>>(xb, wqkvb, qkv, M_TOK, QKV_W,
                                            D_MODEL);
  k_vtrans<<<dim3(32, 2, 16), 256, 0, stream>>>(qkv, vt);
  k_attn<<<512, 512, 0, stream>>>(qkv, vt, ao);
  k_gemm8p<0><<<256, 512, 131072, stream>>>(ao, wob, d_out, M_TOK, D_MODEL,
                                            D_MODEL);
}